// Round 16
// baseline (188.044 us; speedup 1.0000x reference)
//
#include <hip/hip_runtime.h>
#include <stdint.h>

typedef float f32x4 __attribute__((ext_vector_type(4)));
typedef short s16x8 __attribute__((ext_vector_type(8)));
typedef short s16x4 __attribute__((ext_vector_type(4)));

__device__ __forceinline__ short f2bf(float f){
  union { float f; unsigned u; } v; v.f = f;
  unsigned r = v.u + 0x7FFFu + ((v.u >> 16) & 1u);
  return (short)(r >> 16);
}
__device__ __forceinline__ float bf2f(short h){
  union { unsigned u; float f; } v; v.u = ((unsigned)(unsigned short)h) << 16;
  return v.f;
}

// ---------- addcvt block: s_bf[gbid] = bf16(text+image), gbid in [0,8192) ----------
// NT loads: text/image are read exactly once — don't evict s_bf/weights from L2/L3.
__device__ __forceinline__
void addcvt_block(int gbid, int tid, const float* __restrict__ ta,
                  const float* __restrict__ tb, short* __restrict__ so){
  long i = (long)gbid * 256 + tid;
  const f32x4* a4 = (const f32x4*)ta;
  const f32x4* b4 = (const f32x4*)tb;
  f32x4 x0 = __builtin_nontemporal_load(&a4[2*i]);
  f32x4 x1 = __builtin_nontemporal_load(&a4[2*i+1]);
  f32x4 y0 = __builtin_nontemporal_load(&b4[2*i]);
  f32x4 y1 = __builtin_nontemporal_load(&b4[2*i+1]);
  s16x8 r;
  #pragma unroll
  for (int j=0;j<4;j++){ r[j] = f2bf(x0[j]+y0[j]); r[j+4] = f2bf(x1[j]+y1[j]); }
  *(s16x8*)(so + i*8) = r;
}

// ---------- L1: weight prep (blocks 0..6655) + addcvt chunk (6656..9947) ----------
__global__ void k_prep1(const float* __restrict__ ta, const float* __restrict__ tb,
                        short* __restrict__ so,
                        const float* __restrict__ c0s, short* __restrict__ c0d,
                        const float* __restrict__ c1s, short* __restrict__ c1d,
                        const float* __restrict__ c2s, short* __restrict__ c2d,
                        const float* __restrict__ t0s, short* __restrict__ t0d,
                        const float* __restrict__ t1s, short* __restrict__ t1d,
                        const float* __restrict__ t2s, short* __restrict__ t2d,
                        const float* __restrict__ wt, const float* __restrict__ bvt, const float* __restrict__ obt,
                        const float* __restrict__ wi, const float* __restrict__ bvi, const float* __restrict__ obi,
                        float* __restrict__ bc){
  int bid = blockIdx.x;
  int tid = threadIdx.x;
  if (bid >= 6656) { addcvt_block(bid - 6656, tid, ta, tb, so); return; }
  if (bid < 3072) {
    int z = bid >> 10, b = bid & 1023;
    const float* in = (z==0) ? c0s : ((z==1) ? c1s : c2s);
    short* out      = (z==0) ? c0d : ((z==1) ? c1d : c2d);
    long i = (long)b*256 + tid;
    f32x4 v = ((const f32x4*)in)[i];
    s16x4 r;
    #pragma unroll
    for (int j=0;j<4;j++) r[j] = f2bf(v[j]);
    *(s16x4*)(out + i*4) = r;
  } else if (bid < 6144) {
    int q = bid - 3072;
    int z = q >> 10, b = q & 1023;
    const float* in = (z==0) ? t0s : ((z==1) ? t1s : t2s);
    short* out      = (z==0) ? t0d : ((z==1) ? t1d : t2d);
    __shared__ float tile[32][33];
    int tx = tid & 31, ty = tid >> 5;
    int c0 = (b & 31)*32, r0 = (b >> 5)*32;
    #pragma unroll
    for (int i=ty; i<32; i+=8)
      tile[i][tx] = __builtin_nontemporal_load(&in[(long)(r0+i)*1024 + c0 + tx]);
    __syncthreads();
    #pragma unroll
    for (int i=ty; i<32; i+=8)
      out[(long)(c0+i)*1024 + r0 + tx] = f2bf(tile[tx][i]);
  } else {
    int q = bid - 6144;
    int z = q >> 8, b = q & 255;
    const float* w  = z ? wi  : wt;
    const float* bv = z ? bvi : bvt;
    const float* ob = z ? obi : obt;
    int n = b*4 + (tid>>6);
    int lane = tid & 63;
    const float* row = w + (long)n*1024;
    float acc = 0.f;
    for (int j=lane; j<1024; j+=64) acc += row[j]*bv[j];
    #pragma unroll
    for (int m=32;m;m>>=1) acc += __shfl_xor(acc, m, 64);
    if (lane==0) bc[z*1024+n] = acc + ob[n];
  }
}

#define GLDS(src, dst) __builtin_amdgcn_global_load_lds( \
    (const __attribute__((address_space(1))) void*)(src), \
    (__attribute__((address_space(3))) void*)(dst), 16, 0, 0)

// ---------- small NT GEMM body (128x128 tile, m97 structure): C bf16 = A@B^T ----------
__device__ __forceinline__
void gemm_small_body(const short* __restrict__ A, const short* __restrict__ B,
                     short* __restrict__ C, int N, int K, int m0, int n0,
                     short* ldsA, short* ldsB, int tid)
{
  const int lane = tid & 63;
  const int wv = tid >> 6;
  const int wm = wv >> 1, wn = wv & 1;

  f32x4 acc[4][4];
  #pragma unroll
  for (int i=0;i<4;i++)
    #pragma unroll
    for (int j=0;j<4;j++) acc[i][j] = (f32x4){0.f,0.f,0.f,0.f};

  const int bo0 = wv*1024 + lane*16;
  const int bo1 = bo0 + 4096;
  const int r0 = bo0 >> 6, c0 = bo0 & 63;
  const int r1 = bo1 >> 6, c1 = bo1 & 63;
  const long rsb = (long)K * 2;

  const char* Ab = (const char*)A;
  const char* Bb = (const char*)B;
  char* lA = (char*)ldsA;
  char* lB = (char*)ldsB;

  const int nkt = K >> 5;
  for (int kt = 0; kt < nkt; ++kt) {
    const long kb = (long)kt * 64;
    GLDS(Ab + (long)(m0 + r0)*rsb + kb + c0, lA + wv*1024);
    GLDS(Ab + (long)(m0 + r1)*rsb + kb + c1, lA + 4096 + wv*1024);
    GLDS(Bb + (long)(n0 + r0)*rsb + kb + c0, lB + wv*1024);
    GLDS(Bb + (long)(n0 + r1)*rsb + kb + c1, lB + 4096 + wv*1024);
    __syncthreads();

    s16x8 af[4], bfv[4];
    #pragma unroll
    for (int i=0;i<4;i++)
      af[i] = *(const s16x8*)(lA + (wm*64 + i*16 + (lane&15))*64 + (lane>>4)*16);
    #pragma unroll
    for (int j=0;j<4;j++)
      bfv[j] = *(const s16x8*)(lB + (wn*64 + j*16 + (lane&15))*64 + (lane>>4)*16);

    #pragma unroll
    for (int i=0;i<4;i++)
      #pragma unroll
      for (int j=0;j<4;j++)
        acc[i][j] = __builtin_amdgcn_mfma_f32_16x16x32_bf16(af[i], bfv[j], acc[i][j], 0, 0, 0);
    __syncthreads();
  }

  #pragma unroll
  for (int j=0;j<4;j++){
    int gn = n0 + wn*64 + j*16 + (lane&15);
    #pragma unroll
    for (int i=0;i<4;i++){
      int gmb = m0 + wm*64 + i*16 + ((lane>>4)*4);
      #pragma unroll
      for (int r=0;r<4;r++)
        C[(long)(gmb+r)*N + gn] = f2bf(acc[i][j][r]);
    }
  }
}

// ---------- L2: gemm_wc (blocks 0..127) + addcvt chunk (128..2427) ----------
__global__ __launch_bounds__(256, 2)
void k_wc_add(const short* __restrict__ Abase, const short* __restrict__ Bbase,
              short* __restrict__ Cbase, long zA, long zB, long zC,
              const float* __restrict__ ta, const float* __restrict__ tb,
              short* __restrict__ so)
{
  __shared__ __align__(16) short ldsA[128*32];
  __shared__ __align__(16) short ldsB[128*32];
  int bid = blockIdx.x;
  if (bid >= 128) { addcvt_block(3292 + bid - 128, threadIdx.x, ta, tb, so); return; }
  int z = bid >> 6, y = (bid >> 3) & 7, x = bid & 7;
  gemm_small_body(Abase + (long)z*zA, Bbase + (long)z*zB, Cbase + (long)z*zC,
                  1024, 1024, x*128, y*128, ldsA, ldsB, threadIdx.x);
}

// ---------- L3: bias2+copy (0..515) + W2 GEMM (516..643) + addcvt (644..3243) ----------
__global__ __launch_bounds__(256, 2)
void k_b2g2(const short* __restrict__ Wc, const float* __restrict__ fuse_b,
            const float* __restrict__ bc, float* __restrict__ b_all,
            const short* __restrict__ fuse_wT, short* __restrict__ W2,
            const float* __restrict__ ta, const float* __restrict__ tb,
            short* __restrict__ so)
{
  __shared__ __align__(16) short ldsA[128*32];
  __shared__ __align__(16) short ldsB[128*32];
  int bid = blockIdx.x;
  if (bid >= 644) { addcvt_block(5592 + bid - 644, threadIdx.x, ta, tb, so); return; }
  if (bid < 512) {
    int n = bid*4 + (threadIdx.x>>6);
    int lane = threadIdx.x & 63;
    const short* row = Wc + (long)n*1024;
    float acc = 0.f;
    for (int j=lane; j<1024; j+=64) acc += bf2f(row[j])*fuse_b[j];
    #pragma unroll
    for (int m=32;m;m>>=1) acc += __shfl_xor(acc, m, 64);
    if (lane==0) b_all[1024+n] = acc + bc[n];
    return;
  }
  if (bid < 516) {
    int i = (bid - 512)*256 + threadIdx.x;
    b_all[i] = fuse_b[i];
    return;
  }
  int g = bid - 516;                 // 0..127 -> 16 x 8 tiles of 2048x1024
  gemm_small_body(Wc, fuse_wT, W2, 1024, 1024,
                  (g & 15)*128, (g >> 4)*128, ldsA, ldsB, threadIdx.x);
}

// ---------- main NT GEMM: 256x256, BK=64, R7 schedule + zero-VALU addressing ----------
// (R13-verified; R15 NT output stores. Schedule invariants in R6/R7 notes.)
#define MFMA16 __builtin_amdgcn_mfma_f32_16x16x32_bf16
#define VMW4 asm volatile("s_waitcnt vmcnt(4)" ::: "memory")
#define VMW0 asm volatile("s_waitcnt vmcnt(0)" ::: "memory")
#define LGKM0 asm volatile("s_waitcnt lgkmcnt(0)" ::: "memory")
#define MEMF asm volatile("" ::: "memory")

__global__ __launch_bounds__(512, 2)
void gemm_main(const short* __restrict__ A, const short* __restrict__ B,
               float* __restrict__ O, const float* __restrict__ bias,
               int M, int N)
{
  __shared__ __align__(16) char lds[131072];
  constexpr int K = 1024;
  constexpr int nkt = 16;

  const int nbn = N >> 8;
  const int nwg = (M >> 8) * nbn;
  const int cpx = nwg >> 3;
  int bid = blockIdx.x;
  int swz = (bid & 7) * cpx + (bid >> 3);
  const int m0 = (swz / nbn) << 8;
  const int n0 = (swz % nbn) << 8;

  const int tid  = threadIdx.x;
  const int lane = tid & 63;
  const int wid  = tid >> 6;
  const int wm   = wid >> 2;   // 0..1
  const int wn   = wid & 3;    // 0..3
  const long rsb = (long)K * 2;

  f32x4 acc[8][4];
  #pragma unroll
  for (int i=0;i<8;i++)
    #pragma unroll
    for (int j=0;j<4;j++) acc[i][j] = (f32x4){0.f,0.f,0.f,0.f};

  // ---- precomputed LDS read bases (zero per-read VALU) ----
  const int lo0 = (((lane>>4)<<4)) ^ ((lane&7)<<4);
  const int lo1 = lo0 ^ 64;
  const char* pA0 = lds + wm*16384 + (lane&15)*128 + lo0;          // A, ks=0
  const char* pA1 = lds + wm*16384 + (lane&15)*128 + lo1;          // A, ks=1
  const char* pB0 = lds + 65536 + wn*8192 + (lane&15)*128 + lo0;   // B, ks=0
  const char* pB1 = lds + 65536 + wn*8192 + (lane&15)*128 + lo1;   // B, ks=1

  // ---- stage destinations (wave-uniform) + running source pointers ----
  int sdst[2][2];
  const char* Apt[2][2];
  const char* Bpt[2][2];
  #pragma unroll
  for (int H=0;H<2;H++)
    #pragma unroll
    for (int sb=0;sb<2;sb++){
      int c = H*1024 + sb*512 + wid*64 + lane;
      int q = c ^ ((c>>3)&7);
      sdst[H][sb] = (H*1024 + sb*512 + wid*64) << 4;
      const long roff = (long)(q >> 3) * rsb + ((q & 7) << 4);
      Apt[H][sb] = (const char*)A + (long)m0*rsb + roff + 128;  // first use kt=1
      Bpt[H][sb] = (const char*)B + (long)n0*rsb + roff + 256;  // first use kt=2
    }

  // Prologue: A(0)->Abuf0, B(0)->Bbuf0, B(1)->Bbuf1 (12 loads); VMW4 leaves
  // B(1)x4 in flight (drained at ks1(0) VMW0).
  #pragma unroll
  for (int H=0;H<2;H++)
    #pragma unroll
    for (int sb=0;sb<2;sb++)
      GLDS(Apt[H][sb] - 128, lds + sdst[H][sb]);
  #pragma unroll
  for (int H=0;H<2;H++)
    #pragma unroll
    for (int sb=0;sb<2;sb++)
      GLDS(Bpt[H][sb] - 256, lds + 65536 + sdst[H][sb]);
  #pragma unroll
  for (int H=0;H<2;H++)
    #pragma unroll
    for (int sb=0;sb<2;sb++)
      GLDS(Bpt[H][sb] - 128, lds + 98304 + sdst[H][sb]);
  VMW4; MEMF;
  __builtin_amdgcn_s_barrier();

  s16x8 bfr[4][2];
  s16x8 af[8];

  #pragma unroll
  for (int t = 0; t < nkt; ++t) {
    const int RB = (t & 1) << 15;               // compile-time per iteration
    // -------- ks0 phase --------
    #pragma unroll
    for (int j=0;j<4;j++){
      bfr[j][0] = *(const s16x8*)(pB0 + RB + j*2048);
      bfr[j][1] = *(const s16x8*)(pB1 + RB + j*2048);
    }
    #pragma unroll
    for (int i=0;i<8;i++) af[i] = *(const s16x8*)(pA0 + RB + i*2048);
    VMW4; MEMF;
    __builtin_amdgcn_s_barrier();
    if (t+1 < nkt) {
      const int AB2 = ((t+1)&1) << 15;          // compile-time
      #pragma unroll
      for (int H=0;H<2;H++)
        #pragma unroll
        for (int sb=0;sb<2;sb++){
          GLDS(Apt[H][sb], lds + AB2 + sdst[H][sb]);
          Apt[H][sb] += 128;
        }
    }
    LGKM0;
    __builtin_amdgcn_s_setprio(1);
    #pragma unroll
    for (int i=0;i<8;i++)
      #pragma unroll
      for (int j=0;j<4;j++)
        acc[i][j] = MFMA16(af[i], bfr[j][0], acc[i][j], 0, 0, 0);
    __builtin_amdgcn_s_setprio(0);
    // -------- ks1 phase --------
    #pragma unroll
    for (int i=0;i<8;i++) af[i] = *(const s16x8*)(pA1 + RB + i*2048);
    VMW0; MEMF;            // drains B(t+1) AND A(t+1) before the barrier
    __builtin_amdgcn_s_barrier();
    if (t+2 < nkt) {
      const int BB2 = 65536 + RB;               // compile-time
      #pragma unroll
      for (int H=0;H<2;H++)
        #pragma unroll
        for (int sb=0;sb<2;sb++){
          GLDS(Bpt[H][sb], lds + BB2 + sdst[H][sb]);
          Bpt[H][sb] += 128;
        }
    }
    LGKM0;
    __builtin_amdgcn_s_setprio(1);
    #pragma unroll
    for (int i=0;i<8;i++)
      #pragma unroll
      for (int j=0;j<4;j++)
        acc[i][j] = MFMA16(af[i], bfr[j][1], acc[i][j], 0, 0, 0);
    __builtin_amdgcn_s_setprio(0);
  }

  // Epilogue: fp32 + bias, scatter by output region (text | image | fused).
  // Non-temporal stores: output is never re-read; don't evict A/B panels.
  const long BD = (long)M * 1024L;
  #pragma unroll
  for (int j=0;j<4;j++){
    int gn = n0 + wn*64 + j*16 + (lane&15);
    float bb = bias[gn];
    int region = gn >> 10;
    long rbase = (region==0) ? 2*BD : ((region==1) ? 0L : BD);
    int col = gn & 1023;
    #pragma unroll
    for (int i=0;i<8;i++){
      int gr = m0 + wm*128 + i*16 + ((lane>>4)<<2);
      #pragma unroll
      for (int r=0;r<4;r++)
        __builtin_nontemporal_store(acc[i][j][r] + bb,
                                    &O[rbase + (long)(gr+r)*1024 + col]);
    }
  }
}

extern "C" void kernel_launch(void* const* d_in, const int* in_sizes, int n_in,
                              void* d_out, int out_size, void* d_ws, size_t ws_size,
                              hipStream_t stream) {
  const float* text    = (const float*)d_in[0];
  const float* image   = (const float*)d_in[1];
  const float* fuse_w  = (const float*)d_in[2];
  const float* fuse_b  = (const float*)d_in[3];
  const float* t_in_w  = (const float*)d_in[4];
  const float* t_in_b  = (const float*)d_in[5];
  const float* t_out_w = (const float*)d_in[6];
  const float* t_out_b = (const float*)d_in[7];
  const float* i_in_w  = (const float*)d_in[8];
  const float* i_in_b  = (const float*)d_in[9];
  const float* i_out_w = (const float*)d_in[10];
  const float* i_out_b = (const float*)d_in[11];
  float* out = (float*)d_out;

  const long DD = 1024L*1024L;
  char* ws = (char*)d_ws;
  short* s_bf    = (short*)ws; ws += 16384L*1024*2;
  short* W_all   = (short*)ws; ws += 3*DD*2;      // rows: [fuse_w; Wt2; Wi2]
  short* wvT     = (short*)ws; ws += 2*DD*2;      // [wvT_t; wvT_i]
  short* fuse_wT = (short*)ws; ws += DD*2;
  short* outw_st = (short*)ws; ws += 2*DD*2;      // [t_out_w; i_out_w] bf16
  short* Wc_st   = (short*)ws; ws += 2*DD*2;      // [Wc_t; Wc_i]
  float* bc      = (float*)ws; ws += 2048*4;
  float* b_all   = (float*)ws; ws += 3072*4;

  // L1: weight prep + addcvt[0..3292)
  k_prep1<<<9948, 256, 0, stream>>>(text, image, s_bf,
                                    fuse_w, W_all,
                                    t_out_w, outw_st,
                                    i_out_w, outw_st + DD,
                                    t_in_w + 2*DD, wvT,
                                    i_in_w + 2*DD, wvT + DD,
                                    fuse_w, fuse_wT,
                                    t_out_w, t_in_b + 2048, t_out_b,
                                    i_out_w, i_in_b + 2048, i_out_b, bc);

  // L2: Wc_z = out_w_z @ wv_z + addcvt[3292..5592)
  k_wc_add<<<2428, 256, 0, stream>>>(outw_st, wvT, Wc_st, DD, DD, DD,
                                     text, image, s_bf);

  // L3: b_all = [fuse_b ; Wc@fuse_b + bc], W2 = Wc @ fuse_w, addcvt[5592..8192)
  k_b2g2<<<3244, 256, 0, stream>>>(Wc_st, fuse_b, bc, b_all, fuse_wT, W_all + DD,
                                   text, image, s_bf);

  // L4: main C = s @ W_all.T + b_all, scatter into d_out
  gemm_main<<<dim3(768), 512, 0, stream>>>(s_bf, W_all, out, b_all, 16384, 3072);
}

// Round 17
// 179.883 us; speedup vs baseline: 1.0454x; 1.0454x over previous
//
#include <hip/hip_runtime.h>
#include <stdint.h>

typedef float f32x4 __attribute__((ext_vector_type(4)));
typedef short s16x8 __attribute__((ext_vector_type(8)));
typedef short s16x4 __attribute__((ext_vector_type(4)));

__device__ __forceinline__ short f2bf(float f){
  union { float f; unsigned u; } v; v.f = f;
  unsigned r = v.u + 0x7FFFu + ((v.u >> 16) & 1u);
  return (short)(r >> 16);
}
__device__ __forceinline__ float bf2f(short h){
  union { unsigned u; float f; } v; v.u = ((unsigned)(unsigned short)h) << 16;
  return v.f;
}

// ---------- addcvt block: s_bf[gbid] = bf16(text+image), gbid in [0,8192) ----------
__device__ __forceinline__
void addcvt_block(int gbid, int tid, const float* __restrict__ ta,
                  const float* __restrict__ tb, short* __restrict__ so){
  long i = (long)gbid * 256 + tid;
  const f32x4* a4 = (const f32x4*)ta;
  const f32x4* b4 = (const f32x4*)tb;
  f32x4 x0 = a4[2*i], x1 = a4[2*i+1];
  f32x4 y0 = b4[2*i], y1 = b4[2*i+1];
  s16x8 r;
  #pragma unroll
  for (int j=0;j<4;j++){ r[j] = f2bf(x0[j]+y0[j]); r[j+4] = f2bf(x1[j]+y1[j]); }
  *(s16x8*)(so + i*8) = r;
}

// ---------- L1: weight prep (blocks 0..6655) + addcvt chunk (6656..9947) ----------
__global__ void k_prep1(const float* __restrict__ ta, const float* __restrict__ tb,
                        short* __restrict__ so,
                        const float* __restrict__ c0s, short* __restrict__ c0d,
                        const float* __restrict__ c1s, short* __restrict__ c1d,
                        const float* __restrict__ c2s, short* __restrict__ c2d,
                        const float* __restrict__ t0s, short* __restrict__ t0d,
                        const float* __restrict__ t1s, short* __restrict__ t1d,
                        const float* __restrict__ t2s, short* __restrict__ t2d,
                        const float* __restrict__ wt, const float* __restrict__ bvt, const float* __restrict__ obt,
                        const float* __restrict__ wi, const float* __restrict__ bvi, const float* __restrict__ obi,
                        float* __restrict__ bc){
  int bid = blockIdx.x;
  int tid = threadIdx.x;
  if (bid >= 6656) { addcvt_block(bid - 6656, tid, ta, tb, so); return; }
  if (bid < 3072) {
    int z = bid >> 10, b = bid & 1023;
    const float* in = (z==0) ? c0s : ((z==1) ? c1s : c2s);
    short* out      = (z==0) ? c0d : ((z==1) ? c1d : c2d);
    long i = (long)b*256 + tid;
    f32x4 v = ((const f32x4*)in)[i];
    s16x4 r;
    #pragma unroll
    for (int j=0;j<4;j++) r[j] = f2bf(v[j]);
    *(s16x4*)(out + i*4) = r;
  } else if (bid < 6144) {
    int q = bid - 3072;
    int z = q >> 10, b = q & 1023;
    const float* in = (z==0) ? t0s : ((z==1) ? t1s : t2s);
    short* out      = (z==0) ? t0d : ((z==1) ? t1d : t2d);
    __shared__ float tile[32][33];
    int tx = tid & 31, ty = tid >> 5;
    int c0 = (b & 31)*32, r0 = (b >> 5)*32;
    #pragma unroll
    for (int i=ty; i<32; i+=8)
      tile[i][tx] = in[(long)(r0+i)*1024 + c0 + tx];
    __syncthreads();
    #pragma unroll
    for (int i=ty; i<32; i+=8)
      out[(long)(c0+i)*1024 + r0 + tx] = f2bf(tile[tx][i]);
  } else {
    int q = bid - 6144;
    int z = q >> 8, b = q & 255;
    const float* w  = z ? wi  : wt;
    const float* bv = z ? bvi : bvt;
    const float* ob = z ? obi : obt;
    int n = b*4 + (tid>>6);
    int lane = tid & 63;
    const float* row = w + (long)n*1024;
    float acc = 0.f;
    for (int j=lane; j<1024; j+=64) acc += row[j]*bv[j];
    #pragma unroll
    for (int m=32;m;m>>=1) acc += __shfl_xor(acc, m, 64);
    if (lane==0) bc[z*1024+n] = acc + ob[n];
  }
}

#define GLDS(src, dst) __builtin_amdgcn_global_load_lds( \
    (const __attribute__((address_space(1))) void*)(src), \
    (__attribute__((address_space(3))) void*)(dst), 16, 0, 0)

// ---------- small NT GEMM body (128x128 tile, m97 structure): C bf16 = A@B^T ----------
__device__ __forceinline__
void gemm_small_body(const short* __restrict__ A, const short* __restrict__ B,
                     short* __restrict__ C, int N, int K, int m0, int n0,
                     short* ldsA, short* ldsB, int tid)
{
  const int lane = tid & 63;
  const int wv = tid >> 6;
  const int wm = wv >> 1, wn = wv & 1;

  f32x4 acc[4][4];
  #pragma unroll
  for (int i=0;i<4;i++)
    #pragma unroll
    for (int j=0;j<4;j++) acc[i][j] = (f32x4){0.f,0.f,0.f,0.f};

  const int bo0 = wv*1024 + lane*16;
  const int bo1 = bo0 + 4096;
  const int r0 = bo0 >> 6, c0 = bo0 & 63;
  const int r1 = bo1 >> 6, c1 = bo1 & 63;
  const long rsb = (long)K * 2;

  const char* Ab = (const char*)A;
  const char* Bb = (const char*)B;
  char* lA = (char*)ldsA;
  char* lB = (char*)ldsB;

  const int nkt = K >> 5;
  for (int kt = 0; kt < nkt; ++kt) {
    const long kb = (long)kt * 64;
    GLDS(Ab + (long)(m0 + r0)*rsb + kb + c0, lA + wv*1024);
    GLDS(Ab + (long)(m0 + r1)*rsb + kb + c1, lA + 4096 + wv*1024);
    GLDS(Bb + (long)(n0 + r0)*rsb + kb + c0, lB + wv*1024);
    GLDS(Bb + (long)(n0 + r1)*rsb + kb + c1, lB + 4096 + wv*1024);
    __syncthreads();

    s16x8 af[4], bfv[4];
    #pragma unroll
    for (int i=0;i<4;i++)
      af[i] = *(const s16x8*)(lA + (wm*64 + i*16 + (lane&15))*64 + (lane>>4)*16);
    #pragma unroll
    for (int j=0;j<4;j++)
      bfv[j] = *(const s16x8*)(lB + (wn*64 + j*16 + (lane&15))*64 + (lane>>4)*16);

    #pragma unroll
    for (int i=0;i<4;i++)
      #pragma unroll
      for (int j=0;j<4;j++)
        acc[i][j] = __builtin_amdgcn_mfma_f32_16x16x32_bf16(af[i], bfv[j], acc[i][j], 0, 0, 0);
    __syncthreads();
  }

  #pragma unroll
  for (int j=0;j<4;j++){
    int gn = n0 + wn*64 + j*16 + (lane&15);
    #pragma unroll
    for (int i=0;i<4;i++){
      int gmb = m0 + wm*64 + i*16 + ((lane>>4)*4);
      #pragma unroll
      for (int r=0;r<4;r++)
        C[(long)(gmb+r)*N + gn] = f2bf(acc[i][j][r]);
    }
  }
}

// ---------- L2: gemm_wc (blocks 0..127) + addcvt chunk (128..2427) ----------
__global__ __launch_bounds__(256, 2)
void k_wc_add(const short* __restrict__ Abase, const short* __restrict__ Bbase,
              short* __restrict__ Cbase, long zA, long zB, long zC,
              const float* __restrict__ ta, const float* __restrict__ tb,
              short* __restrict__ so)
{
  __shared__ __align__(16) short ldsA[128*32];
  __shared__ __align__(16) short ldsB[128*32];
  int bid = blockIdx.x;
  if (bid >= 128) { addcvt_block(3292 + bid - 128, threadIdx.x, ta, tb, so); return; }
  int z = bid >> 6, y = (bid >> 3) & 7, x = bid & 7;
  gemm_small_body(Abase + (long)z*zA, Bbase + (long)z*zB, Cbase + (long)z*zC,
                  1024, 1024, x*128, y*128, ldsA, ldsB, threadIdx.x);
}

// ---------- L3: bias2+copy (0..515) + W2 GEMM (516..643) + addcvt (644..3243) ----------
__global__ __launch_bounds__(256, 2)
void k_b2g2(const short* __restrict__ Wc, const float* __restrict__ fuse_b,
            const float* __restrict__ bc, float* __restrict__ b_all,
            const short* __restrict__ fuse_wT, short* __restrict__ W2,
            const float* __restrict__ ta, const float* __restrict__ tb,
            short* __restrict__ so)
{
  __shared__ __align__(16) short ldsA[128*32];
  __shared__ __align__(16) short ldsB[128*32];
  int bid = blockIdx.x;
  if (bid >= 644) { addcvt_block(5592 + bid - 644, threadIdx.x, ta, tb, so); return; }
  if (bid < 512) {
    int n = bid*4 + (threadIdx.x>>6);
    int lane = threadIdx.x & 63;
    const short* row = Wc + (long)n*1024;
    float acc = 0.f;
    for (int j=lane; j<1024; j+=64) acc += bf2f(row[j])*fuse_b[j];
    #pragma unroll
    for (int m=32;m;m>>=1) acc += __shfl_xor(acc, m, 64);
    if (lane==0) b_all[1024+n] = acc + bc[n];
    return;
  }
  if (bid < 516) {
    int i = (bid - 512)*256 + threadIdx.x;
    b_all[i] = fuse_b[i];
    return;
  }
  int g = bid - 516;                 // 0..127 -> 16 x 8 tiles of 2048x1024
  gemm_small_body(Wc, fuse_wT, W2, 1024, 1024,
                  (g & 15)*128, (g >> 4)*128, ldsA, ldsB, threadIdx.x);
}

// ---------- main NT GEMM: 256x256, BK=64, R7 schedule + zero-VALU addressing ----------
// (R13-verified; R15 adds non-temporal output stores — C is never re-read, so
// bypassing L2 preserves the A/B panel working set. Schedule invariants in
// R6/R7 notes. R17 = R15 exact revert: NT loads (R16) regressed, removed.)
#define MFMA16 __builtin_amdgcn_mfma_f32_16x16x32_bf16
#define VMW4 asm volatile("s_waitcnt vmcnt(4)" ::: "memory")
#define VMW0 asm volatile("s_waitcnt vmcnt(0)" ::: "memory")
#define LGKM0 asm volatile("s_waitcnt lgkmcnt(0)" ::: "memory")
#define MEMF asm volatile("" ::: "memory")

__global__ __launch_bounds__(512, 2)
void gemm_main(const short* __restrict__ A, const short* __restrict__ B,
               float* __restrict__ O, const float* __restrict__ bias,
               int M, int N)
{
  __shared__ __align__(16) char lds[131072];
  constexpr int K = 1024;
  constexpr int nkt = 16;

  const int nbn = N >> 8;
  const int nwg = (M >> 8) * nbn;
  const int cpx = nwg >> 3;
  int bid = blockIdx.x;
  int swz = (bid & 7) * cpx + (bid >> 3);
  const int m0 = (swz / nbn) << 8;
  const int n0 = (swz % nbn) << 8;

  const int tid  = threadIdx.x;
  const int lane = tid & 63;
  const int wid  = tid >> 6;
  const int wm   = wid >> 2;   // 0..1
  const int wn   = wid & 3;    // 0..3
  const long rsb = (long)K * 2;

  f32x4 acc[8][4];
  #pragma unroll
  for (int i=0;i<8;i++)
    #pragma unroll
    for (int j=0;j<4;j++) acc[i][j] = (f32x4){0.f,0.f,0.f,0.f};

  // ---- precomputed LDS read bases (zero per-read VALU) ----
  const int lo0 = (((lane>>4)<<4)) ^ ((lane&7)<<4);
  const int lo1 = lo0 ^ 64;
  const char* pA0 = lds + wm*16384 + (lane&15)*128 + lo0;          // A, ks=0
  const char* pA1 = lds + wm*16384 + (lane&15)*128 + lo1;          // A, ks=1
  const char* pB0 = lds + 65536 + wn*8192 + (lane&15)*128 + lo0;   // B, ks=0
  const char* pB1 = lds + 65536 + wn*8192 + (lane&15)*128 + lo1;   // B, ks=1

  // ---- stage destinations (wave-uniform) + running source pointers ----
  int sdst[2][2];
  const char* Apt[2][2];
  const char* Bpt[2][2];
  #pragma unroll
  for (int H=0;H<2;H++)
    #pragma unroll
    for (int sb=0;sb<2;sb++){
      int c = H*1024 + sb*512 + wid*64 + lane;
      int q = c ^ ((c>>3)&7);
      sdst[H][sb] = (H*1024 + sb*512 + wid*64) << 4;
      const long roff = (long)(q >> 3) * rsb + ((q & 7) << 4);
      Apt[H][sb] = (const char*)A + (long)m0*rsb + roff + 128;  // first use kt=1
      Bpt[H][sb] = (const char*)B + (long)n0*rsb + roff + 256;  // first use kt=2
    }

  // Prologue: A(0)->Abuf0, B(0)->Bbuf0, B(1)->Bbuf1 (12 loads); VMW4 leaves
  // B(1)x4 in flight (drained at ks1(0) VMW0).
  #pragma unroll
  for (int H=0;H<2;H++)
    #pragma unroll
    for (int sb=0;sb<2;sb++)
      GLDS(Apt[H][sb] - 128, lds + sdst[H][sb]);
  #pragma unroll
  for (int H=0;H<2;H++)
    #pragma unroll
    for (int sb=0;sb<2;sb++)
      GLDS(Bpt[H][sb] - 256, lds + 65536 + sdst[H][sb]);
  #pragma unroll
  for (int H=0;H<2;H++)
    #pragma unroll
    for (int sb=0;sb<2;sb++)
      GLDS(Bpt[H][sb] - 128, lds + 98304 + sdst[H][sb]);
  VMW4; MEMF;
  __builtin_amdgcn_s_barrier();

  s16x8 bfr[4][2];
  s16x8 af[8];

  #pragma unroll
  for (int t = 0; t < nkt; ++t) {
    const int RB = (t & 1) << 15;               // compile-time per iteration
    // -------- ks0 phase --------
    #pragma unroll
    for (int j=0;j<4;j++){
      bfr[j][0] = *(const s16x8*)(pB0 + RB + j*2048);
      bfr[j][1] = *(const s16x8*)(pB1 + RB + j*2048);
    }
    #pragma unroll
    for (int i=0;i<8;i++) af[i] = *(const s16x8*)(pA0 + RB + i*2048);
    VMW4; MEMF;
    __builtin_amdgcn_s_barrier();
    if (t+1 < nkt) {
      const int AB2 = ((t+1)&1) << 15;          // compile-time
      #pragma unroll
      for (int H=0;H<2;H++)
        #pragma unroll
        for (int sb=0;sb<2;sb++){
          GLDS(Apt[H][sb], lds + AB2 + sdst[H][sb]);
          Apt[H][sb] += 128;
        }
    }
    LGKM0;
    __builtin_amdgcn_s_setprio(1);
    #pragma unroll
    for (int i=0;i<8;i++)
      #pragma unroll
      for (int j=0;j<4;j++)
        acc[i][j] = MFMA16(af[i], bfr[j][0], acc[i][j], 0, 0, 0);
    __builtin_amdgcn_s_setprio(0);
    // -------- ks1 phase --------
    #pragma unroll
    for (int i=0;i<8;i++) af[i] = *(const s16x8*)(pA1 + RB + i*2048);
    VMW0; MEMF;            // drains B(t+1) AND A(t+1) before the barrier
    __builtin_amdgcn_s_barrier();
    if (t+2 < nkt) {
      const int BB2 = 65536 + RB;               // compile-time
      #pragma unroll
      for (int H=0;H<2;H++)
        #pragma unroll
        for (int sb=0;sb<2;sb++){
          GLDS(Bpt[H][sb], lds + BB2 + sdst[H][sb]);
          Bpt[H][sb] += 128;
        }
    }
    LGKM0;
    __builtin_amdgcn_s_setprio(1);
    #pragma unroll
    for (int i=0;i<8;i++)
      #pragma unroll
      for (int j=0;j<4;j++)
        acc[i][j] = MFMA16(af[i], bfr[j][1], acc[i][j], 0, 0, 0);
    __builtin_amdgcn_s_setprio(0);
  }

  // Epilogue: fp32 + bias, scatter by output region (text | image | fused).
  // Non-temporal stores: output is never re-read; don't evict A/B panels.
  const long BD = (long)M * 1024L;
  #pragma unroll
  for (int j=0;j<4;j++){
    int gn = n0 + wn*64 + j*16 + (lane&15);
    float bb = bias[gn];
    int region = gn >> 10;
    long rbase = (region==0) ? 2*BD : ((region==1) ? 0L : BD);
    int col = gn & 1023;
    #pragma unroll
    for (int i=0;i<8;i++){
      int gr = m0 + wm*128 + i*16 + ((lane>>4)<<2);
      #pragma unroll
      for (int r=0;r<4;r++)
        __builtin_nontemporal_store(acc[i][j][r] + bb,
                                    &O[rbase + (long)(gr+r)*1024 + col]);
    }
  }
}

extern "C" void kernel_launch(void* const* d_in, const int* in_sizes, int n_in,
                              void* d_out, int out_size, void* d_ws, size_t ws_size,
                              hipStream_t stream) {
  const float* text    = (const float*)d_in[0];
  const float* image   = (const float*)d_in[1];
  const float* fuse_w  = (const float*)d_in[2];
  const float* fuse_b  = (const float*)d_in[3];
  const float* t_in_w  = (const float*)d_in[4];
  const float* t_in_b  = (const float*)d_in[5];
  const float* t_out_w = (const float*)d_in[6];
  const float* t_out_b = (const float*)d_in[7];
  const float* i_in_w  = (const float*)d_in[8];
  const float* i_in_b  = (const float*)d_in[9];
  const float* i_out_w = (const float*)d_in[10];
  const float* i_out_b = (const float*)d_in[11];
  float* out = (float*)d_out;

  const long DD = 1024L*1024L;
  char* ws = (char*)d_ws;
  short* s_bf    = (short*)ws; ws += 16384L*1024*2;
  short* W_all   = (short*)ws; ws += 3*DD*2;      // rows: [fuse_w; Wt2; Wi2]
  short* wvT     = (short*)ws; ws += 2*DD*2;      // [wvT_t; wvT_i]
  short* fuse_wT = (short*)ws; ws += DD*2;
  short* outw_st = (short*)ws; ws += 2*DD*2;      // [t_out_w; i_out_w] bf16
  short* Wc_st   = (short*)ws; ws += 2*DD*2;      // [Wc_t; Wc_i]
  float* bc      = (float*)ws; ws += 2048*4;
  float* b_all   = (float*)ws; ws += 3072*4;

  // L1: weight prep + addcvt[0..3292)
  k_prep1<<<9948, 256, 0, stream>>>(text, image, s_bf,
                                    fuse_w, W_all,
                                    t_out_w, outw_st,
                                    i_out_w, outw_st + DD,
                                    t_in_w + 2*DD, wvT,
                                    i_in_w + 2*DD, wvT + DD,
                                    fuse_w, fuse_wT,
                                    t_out_w, t_in_b + 2048, t_out_b,
                                    i_out_w, i_in_b + 2048, i_out_b, bc);

  // L2: Wc_z = out_w_z @ wv_z + addcvt[3292..5592)
  k_wc_add<<<2428, 256, 0, stream>>>(outw_st, wvT, Wc_st, DD, DD, DD,
                                     text, image, s_bf);

  // L3: b_all = [fuse_b ; Wc@fuse_b + bc], W2 = Wc @ fuse_w, addcvt[5592..8192)
  k_b2g2<<<3244, 256, 0, stream>>>(Wc_st, fuse_b, bc, b_all, fuse_wT, W_all + DD,
                                   text, image, s_bf);

  // L4: main C = s @ W_all.T + b_all, scatter into d_out
  gemm_main<<<dim3(768), 512, 0, stream>>>(s_bf, W_all, out, b_all, 16384, 3072);
}